// Round 15
// baseline (206.595 us; speedup 1.0000x reference)
//
#include <hip/hip_runtime.h>
#include <stdint.h>

#define BN_ 8192
#define DK_ 256
#define LOG2E 1.4426950408889634f
#define LN2 0.6931471805599453f

typedef __attribute__((ext_vector_type(4))) float f32x4;
typedef __attribute__((ext_vector_type(8))) short short8;
typedef __attribute__((ext_vector_type(8))) __bf16 bf16x8;
typedef __attribute__((ext_vector_type(4))) unsigned short us4;

// RNE float -> bf16
__device__ __forceinline__ unsigned short f2bf(float f) {
  unsigned u = __float_as_uint(f);
  u = (u + 0x7fffu + ((u >> 16) & 1u)) >> 16;
  return (unsigned short)u;
}

// async global->LDS, 16B/lane; LDS dest wave-uniform base + lane*16, global src per-lane
#define GLD16(gp, lp)                                                   \
  __builtin_amdgcn_global_load_lds(                                     \
      (__attribute__((address_space(1))) void*)(gp),                    \
      (__attribute__((address_space(3))) void*)(lp), 16, 0, 0)

#define BAR() __builtin_amdgcn_s_barrier()
#define VM0() asm volatile("s_waitcnt vmcnt(0)" ::: "memory")

// ---------------- Kernel 1: row-normalize fp32 -> bf16 (h,l scaled by log2e) ----------------
__global__ __launch_bounds__(256) void norm_kernel(
    const float* __restrict__ hf, const float* __restrict__ lf,
    const float* __restrict__ af,
    unsigned short* __restrict__ hn, unsigned short* __restrict__ ln,
    unsigned short* __restrict__ an) {
  const int tid = threadIdx.x;
  const int w = tid >> 6, lane = tid & 63;
  const int grow = blockIdx.x * 4 + w;
  const int m = grow >> 13;
  const int r = grow & (BN_ - 1);
  const float* src = (m == 0) ? hf : (m == 1) ? lf : af;
  unsigned short* dst = (m == 0) ? hn : (m == 1) ? ln : an;
  const float4 v = ((const float4*)(src + (size_t)r * DK_))[lane];
  float ss = v.x * v.x + v.y * v.y + v.z * v.z + v.w * v.w;
#pragma unroll
  for (int mk = 32; mk >= 1; mk >>= 1) ss += __shfl_xor(ss, mk, 64);
  float inv = 1.0f / fmaxf(sqrtf(ss), 1e-8f);
  if (m != 2) inv *= LOG2E;
  us4 o;
  o.x = f2bf(v.x * inv);
  o.y = f2bf(v.y * inv);
  o.z = f2bf(v.z * inv);
  o.w = f2bf(v.w * inv);
  *(us4*)(dst + (size_t)r * DK_ + lane * 4) = o;
}

// ---------------- Kernel 2: fused GEMM + exp2-row-sum + diag ----------------
// A = [hn;ln] stacked [16384,256], B = an [8192,256], S = A·B^T.
// 256 blocks, 512 thr (8 waves 2Mx4N), tile 256x256, 8 col-tiles/block,
// 64 BK=32 units in 32 BK=64 barrier WINDOWS (R14 structure).
// NEW (R15): wave-phase STAGGER -- odd waves run the window's two units in
// reverse order. Both slots are resident after the window barrier, so order
// is free; this de-phases the CU so half the waves MFMA while half read,
// overlapping the LDS (~1410cy) and MFMA (~1242cy) pipes that R14 showed
// running in SUM (2870cy/unit) instead of MAX.
__global__ __launch_bounds__(512, 2) void gemm_lse_kernel(
    const unsigned short* __restrict__ hl, const unsigned short* __restrict__ an,
    float* __restrict__ sumexp /*[16384]*/, float* __restrict__ diag /*[16384]*/) {
  extern __shared__ char lds[];  // 4 * 32KB = 128KB

  const int tid = threadIdx.x;
  const int lane = tid & 63, w = tid >> 6;
  const int wr = w >> 2, wc = w & 3;
  const int lmod = lane & 15, lhalf = lane >> 4;

  const int bid = blockIdx.x;
  const int swz = (bid & 7) * 32 + (bid >> 3);  // bijective on 256, XCD-grouping
  const int mt = swz >> 2;                      // row tile 0..63
  const int cg = swz & 3;                       // col group (8 tiles each)

  // ---- stage-side constants (32KB unit layout verified R3/R5/R10/R11) ----
  const int isB = ((lane >> 2) ^ (lane >> 5)) & 1;
  const int lcst = (lane & 3) ^ ((lane >> 3) & 3);
  const int rbase = w * 32 + (lane >> 3);
  const char* myBase =
      (isB ? (const char*)an : (const char*)hl + (size_t)mt * 131072) +
      (size_t)rbase * 512 + lcst * 16;
  char* ldsW = lds + w * 4096 + lane * 16;

  // ---- read-side constants ----
  const int xsw = 16 * (lhalf ^ (lmod & 3));
  const int aoff = wr * 16384 + lmod * 128 + 64 * ((lmod >> 2) & 1) + xsw;
  const int boff = wc * 8192 + lmod * 128 + 64 * (1 ^ ((lmod >> 2) & 1)) + xsw;

#define STAGE(uu)                                                        \
  do {                                                                   \
    const int u_ = (uu) & 63;                                            \
    const int kb_ = ((u_ >> 1) & 3) * 128 + (u_ & 1) * 64;               \
    const int nto_ = (cg * 8 + (u_ >> 3)) * 131072 + kb_;                \
    const char* s_ = myBase + (isB ? nto_ : kb_);                        \
    char* d_ = ldsW + ((uu) & 3) * 32768;                                \
    GLD16(s_, d_);                                                       \
    GLD16(s_ + 4096, d_ + 1024);                                         \
    GLD16(s_ + 8192, d_ + 2048);                                         \
    GLD16(s_ + 12288, d_ + 3072);                                        \
  } while (0)

#define LD8(dst, base, off)                                              \
  dst = __builtin_bit_cast(bf16x8, *(const short8*)((base) + (off)))

// one BK=32 unit: reads (12 x b128), optional stage, 32 MFMA in 2 clusters
#define UNIT(U, DO_STAGE)                                                \
  do {                                                                   \
    const char* L = lds + (((U) & 3) * 32768);                           \
    bf16x8 bf[4], af0[4], af1[4];                                        \
    _Pragma("unroll") for (int n = 0; n < 4; ++n)                        \
        LD8(bf[n], L, boff + n * 2048);                                  \
    _Pragma("unroll") for (int m = 0; m < 4; ++m)                        \
        LD8(af0[m], L, aoff + m * 2048);                                 \
    if (DO_STAGE) STAGE((U) + 2);                                        \
    __builtin_amdgcn_s_setprio(1);                                       \
    _Pragma("unroll") for (int m = 0; m < 4; ++m)                        \
    _Pragma("unroll") for (int n = 0; n < 4; ++n)                        \
        acc[m][n] = __builtin_amdgcn_mfma_f32_16x16x32_bf16(             \
            af0[m], bf[n], acc[m][n], 0, 0, 0);                          \
    __builtin_amdgcn_s_setprio(0);                                       \
    _Pragma("unroll") for (int m = 0; m < 4; ++m)                        \
        LD8(af1[m], L, aoff + (m + 4) * 2048);                           \
    __builtin_amdgcn_s_setprio(1);                                       \
    _Pragma("unroll") for (int m = 0; m < 4; ++m)                        \
    _Pragma("unroll") for (int n = 0; n < 4; ++n)                        \
        acc[m + 4][n] = __builtin_amdgcn_mfma_f32_16x16x32_bf16(         \
            af1[m], bf[n], acc[m + 4][n], 0, 0, 0);                      \
    __builtin_amdgcn_s_setprio(0);                                       \
  } while (0)

  float rsum[8][4];
#pragma unroll
  for (int m = 0; m < 8; ++m)
#pragma unroll
    for (int r = 0; r < 4; ++r) rsum[m][r] = 0.0f;

  // prologue: fill pipeline 2 units deep
  STAGE(0);
  STAGE(1);

#pragma unroll 1
  for (int i = 0; i < 8; ++i) {
    f32x4 acc[8][4];
#pragma unroll
    for (int m = 0; m < 8; ++m)
#pragma unroll
      for (int n = 0; n < 4; ++n) acc[m][n] = f32x4{0.f, 0.f, 0.f, 0.f};

#pragma unroll
    for (int ww = 0; ww < 4; ++ww) {
      const int u = i * 8 + ww * 2;
      VM0();   // my stages u,u+1 (issued a full window ago) retired
      BAR();   // collective: slots u,u+1 resident; window w-1 reads done
      if (w & 1) {   // wave-uniform stagger: odd waves reverse unit order
        UNIT(u + 1, (u + 3 < 64));
        UNIT(u, (u + 2 < 64));
      } else {
        UNIT(u, (u + 2 < 64));
        UNIT(u + 1, (u + 3 < 64));
      }
    }

    // ---- tile epilogue: diag (rare) + exp2 into persistent rsum ----
    if (cg * 8 + i == (mt & 31)) {
#pragma unroll
      for (int m = 0; m < 8; ++m)
#pragma unroll
        for (int n = 0; n < 4; ++n)
#pragma unroll
          for (int r = 0; r < 4; ++r) {
            const int row_t = wr * 128 + m * 16 + lhalf * 4 + r;
            const int col_t = wc * 64 + n * 16 + lmod;
            if (row_t == col_t)
              diag[(mt >> 5) * BN_ + (mt & 31) * 256 + row_t] = acc[m][n][r] * LN2;
          }
    }
#pragma unroll
    for (int m = 0; m < 8; ++m)
#pragma unroll
      for (int n = 0; n < 4; ++n)
#pragma unroll
        for (int r = 0; r < 4; ++r)
          rsum[m][r] += __builtin_amdgcn_exp2f(acc[m][n][r]);
  }

  // ---- final: reduce across 16 col-lanes, then atomicAdd ----
#pragma unroll
  for (int m = 0; m < 8; ++m)
#pragma unroll
    for (int r = 0; r < 4; ++r) {
      float v = rsum[m][r];
      v += __shfl_xor(v, 1, 64);
      v += __shfl_xor(v, 2, 64);
      v += __shfl_xor(v, 4, 64);
      v += __shfl_xor(v, 8, 64);
      if (lmod == 0)
        atomicAdd(&sumexp[(mt >> 5) * BN_ + (mt & 31) * 256 + wr * 128 + m * 16 + lhalf * 4 + r], v);
    }
#undef STAGE
#undef LD8
#undef UNIT
}

// ---------------- Kernel 3: CE = mean(log(sumexp) - diag) ----------------
__global__ __launch_bounds__(1024) void finalize_kernel(
    const float* __restrict__ sumexp, const float* __restrict__ diag,
    float* __restrict__ out) {
  const int tid = threadIdx.x;
  float s = 0.0f;
  for (int i = tid; i < 2 * BN_; i += 1024) s += logf(sumexp[i]) - diag[i];
#pragma unroll
  for (int mk = 32; mk >= 1; mk >>= 1) s += __shfl_xor(s, mk, 64);
  __shared__ float red[16];
  if ((tid & 63) == 0) red[tid >> 6] = s;
  __syncthreads();
  if (tid == 0) {
    float t = 0.f;
#pragma unroll
    for (int j = 0; j < 16; ++j) t += red[j];
    out[0] = t * (1.0f / (float)BN_);
  }
}

extern "C" void kernel_launch(void* const* d_in, const int* in_sizes, int n_in,
                              void* d_out, int out_size, void* d_ws, size_t ws_size,
                              hipStream_t stream) {
  const float* hf = (const float*)d_in[0];
  const float* lf = (const float*)d_in[1];
  const float* af = (const float*)d_in[2];

  char* ws = (char*)d_ws;
  const size_t nmat = (size_t)BN_ * DK_;
  unsigned short* hn = (unsigned short*)ws;          // 4 MB (hn,ln contiguous = stacked A)
  unsigned short* ln = hn + nmat;                    // 4 MB
  unsigned short* an = ln + nmat;                    // 4 MB
  float* sumexp = (float*)(ws + 3 * nmat * sizeof(unsigned short));  // 64 KB [16384]
  float* diag = sumexp + 2 * BN_;                                    // 64 KB [16384]

  hipFuncSetAttribute((const void*)gemm_lse_kernel,
                      hipFuncAttributeMaxDynamicSharedMemorySize, 131072);

  hipMemsetAsync(sumexp, 0, 2 * BN_ * sizeof(float), stream);
  norm_kernel<<<(3 * BN_) / 4, 256, 0, stream>>>(hf, lf, af, hn, ln, an);
  gemm_lse_kernel<<<256, 512, 131072, stream>>>(hn, an, sumexp, diag);
  finalize_kernel<<<1, 1024, 0, stream>>>(sumexp, diag, (float*)d_out);
}

// Round 16
// 82.101 us; speedup vs baseline: 2.5164x; 2.5164x over previous
//
#include <hip/hip_runtime.h>
#include <stdint.h>

#define BN_ 8192
#define DK_ 256
#define LOG2E 1.4426950408889634f
// int8 quantization: q = round(127*x); dot in [-16129*256, ...] fits i32 exactly
#define INVQ (1.0f / 16129.0f)          // 1/127^2: acc -> natural-units sim
#define KQ   (LOG2E / 16129.0f)          // acc -> log2-units sim

typedef __attribute__((ext_vector_type(4))) float f32x4;
typedef __attribute__((ext_vector_type(4))) int i32x4;

// async global->LDS, 16B/lane; LDS dest wave-uniform base + lane*16, global src per-lane
#define GLD16(gp, lp)                                                   \
  __builtin_amdgcn_global_load_lds(                                     \
      (__attribute__((address_space(1))) void*)(gp),                    \
      (__attribute__((address_space(3))) void*)(lp), 16, 0, 0)

#define BAR() __builtin_amdgcn_s_barrier()
#define VM0() asm volatile("s_waitcnt vmcnt(0)" ::: "memory")

// ---------------- Kernel 1: row-normalize fp32 -> int8 (x127) ----------------
__global__ __launch_bounds__(256) void norm_kernel(
    const float* __restrict__ hf, const float* __restrict__ lf,
    const float* __restrict__ af, unsigned char* __restrict__ qbase) {
  const int tid = threadIdx.x;
  const int w = tid >> 6, lane = tid & 63;
  const int grow = blockIdx.x * 4 + w;
  const int m = grow >> 13;
  const int r = grow & (BN_ - 1);
  const float* src = (m == 0) ? hf : (m == 1) ? lf : af;
  unsigned char* dst = qbase + (size_t)m * BN_ * DK_;
  const float4 v = ((const float4*)(src + (size_t)r * DK_))[lane];
  float ss = v.x * v.x + v.y * v.y + v.z * v.z + v.w * v.w;
#pragma unroll
  for (int mk = 32; mk >= 1; mk >>= 1) ss += __shfl_xor(ss, mk, 64);
  const float inv = 127.0f / fmaxf(sqrtf(ss), 1e-8f);
  const int q0 = (int)rintf(v.x * inv), q1 = (int)rintf(v.y * inv);
  const int q2 = (int)rintf(v.z * inv), q3 = (int)rintf(v.w * inv);
  const unsigned pk = (q0 & 255) | ((q1 & 255) << 8) | ((q2 & 255) << 16) |
                      ((unsigned)(q3 & 255) << 24);
  *(unsigned*)(dst + (size_t)r * DK_ + lane * 4) = pk;
}

// ---------------- Kernel 2: fused int8-GEMM + exp2-row-sum + diag ----------------
// A = [hq;lq] stacked [16384,256] i8, B = aq [8192,256] i8, S = A·B^T (i32 exact).
// 256 blocks, 512 thr (8 waves 2Mx4N), tile 256x256, 8 col-tiles/block,
// 32 BK=64 units in 16 windows of 2 units (R14-proven skeleton, barriers halved).
// LDS: 4-slot queue, 32KB/slot = A 16K + B 16K. Rows are 64B; 16B slots
// XOR-swizzled by (row>>1)&3 (pre-swizzled global source, linear dest;
// read-side 8 distinct 4-bank bases -> conflict-free).
// mfma_i32_16x16x64_i8: 2x bf16 FLOP rate, half the LDS bytes per K.
__global__ __launch_bounds__(512, 2) void gemm_lse_kernel(
    const unsigned char* __restrict__ hl, const unsigned char* __restrict__ an,
    float* __restrict__ sumexp /*[16384]*/, float* __restrict__ diag /*[16384]*/) {
  extern __shared__ char lds[];  // 4 * 32KB = 128KB

  const int tid = threadIdx.x;
  const int lane = tid & 63, w = tid >> 6;
  const int wr = w >> 2, wc = w & 3;
  const int lmod = lane & 15, lhalf = lane >> 4;

  const int bid = blockIdx.x;
  const int swz = (bid & 7) * 32 + (bid >> 3);  // bijective on 256, XCD-grouping
  const int mt = swz >> 2;                      // row tile 0..63
  const int cg = swz & 3;                       // col group (8 tiles each)

  // ---- stage-side constants ----
  // lane l, load j stages row r = w*32 + j*16 + (l>>2), phys 16B-slot (l&3);
  // logical slot = (l&3) ^ ((l>>3)&3)  (== (l&3) ^ ((r>>1)&3))
  const int rb = w * 32 + (lane >> 2);
  const int slog16 = (((lane & 3) ^ ((lane >> 3) & 3))) * 16;
  const unsigned char* aS0 = hl + ((size_t)(mt * 256 + rb)) * DK_ + slog16;
  const unsigned char* bS0 = an + (size_t)rb * DK_ + slog16;
  char* ldsS = lds + w * 2048 + lane * 16;

  // ---- read-side: A row ar=wr*128+m*16+lmod, k-slot lhalf at
  // phys = ar*64 + 16*(lhalf ^ ((ar>>1)&3));  (ar>>1)&3 == (lmod>>1)&3
  const int rdoff = lmod * 64 + 16 * (lhalf ^ ((lmod >> 1) & 3));
  const int aoffb = wr * 8192 + rdoff;
  const int boffb = 16384 + wc * 4096 + rdoff;

#define STAGE(uu)                                                        \
  do {                                                                   \
    const int u_ = (uu) & 31;                                            \
    const int kb_ = (u_ & 3) * 64;                                       \
    const size_t nto_ = (size_t)(cg * 8 + (u_ >> 2)) * 65536 + kb_;      \
    char* d_ = ldsS + (((uu) & 3) * 32768);                              \
    GLD16(aS0 + kb_, d_);                                                \
    GLD16(aS0 + 4096 + kb_, d_ + 1024);                                  \
    GLD16(bS0 + nto_, d_ + 16384);                                       \
    GLD16(bS0 + 4096 + nto_, d_ + 16384 + 1024);                         \
  } while (0)

#define LD16(dst, base, off) dst = *(const i32x4*)((base) + (off))

// one BK=64 unit: 12 x b128 reads, optional stage, 32 x mfma_i32_16x16x64_i8
#define UNIT(U, DO_STAGE)                                                \
  do {                                                                   \
    const char* L = lds + (((U) & 3) * 32768);                           \
    i32x4 bf[4], af0[4], af1[4];                                         \
    _Pragma("unroll") for (int n = 0; n < 4; ++n)                        \
        LD16(bf[n], L, boffb + n * 1024);                                \
    _Pragma("unroll") for (int m = 0; m < 4; ++m)                        \
        LD16(af0[m], L, aoffb + m * 1024);                               \
    if (DO_STAGE) STAGE((U) + 2);                                        \
    __builtin_amdgcn_s_setprio(1);                                       \
    _Pragma("unroll") for (int m = 0; m < 4; ++m)                        \
    _Pragma("unroll") for (int n = 0; n < 4; ++n)                        \
        acc[m][n] = __builtin_amdgcn_mfma_i32_16x16x64_i8(               \
            af0[m], bf[n], acc[m][n], 0, 0, 0);                          \
    __builtin_amdgcn_s_setprio(0);                                       \
    _Pragma("unroll") for (int m = 0; m < 4; ++m)                        \
        LD16(af1[m], L, aoffb + (m + 4) * 1024);                         \
    __builtin_amdgcn_s_setprio(1);                                       \
    _Pragma("unroll") for (int m = 0; m < 4; ++m)                        \
    _Pragma("unroll") for (int n = 0; n < 4; ++n)                        \
        acc[m + 4][n] = __builtin_amdgcn_mfma_i32_16x16x64_i8(           \
            af1[m], bf[n], acc[m + 4][n], 0, 0, 0);                      \
    __builtin_amdgcn_s_setprio(0);                                       \
  } while (0)

  float rsum[8][4];
#pragma unroll
  for (int m = 0; m < 8; ++m)
#pragma unroll
    for (int r = 0; r < 4; ++r) rsum[m][r] = 0.0f;

  // prologue: fill pipeline 2 units deep
  STAGE(0);
  STAGE(1);

#pragma unroll 1
  for (int i = 0; i < 8; ++i) {   // 8 col-tiles; 4 BK=64 units each = 2 windows
    i32x4 acc[8][4];
#pragma unroll
    for (int m = 0; m < 8; ++m)
#pragma unroll
      for (int n = 0; n < 4; ++n) acc[m][n] = i32x4{0, 0, 0, 0};

#pragma unroll
    for (int ww = 0; ww < 2; ++ww) {
      const int u = i * 4 + ww * 2;
      VM0();   // my stages u,u+1 (issued a full window ago) retired
      BAR();   // collective: slots u,u+1 resident; window w-1 reads done
      UNIT(u, (u + 2 < 32));       // reads(u) | STAGE(u+2) | MFMA(u)
      UNIT(u + 1, (u + 3 < 32));   // reads(u+1) | STAGE(u+3) | MFMA(u+1)
    }

    // ---- tile epilogue: diag (rare) + exp2 into persistent rsum ----
    if (cg * 8 + i == (mt & 31)) {
#pragma unroll
      for (int m = 0; m < 8; ++m)
#pragma unroll
        for (int n = 0; n < 4; ++n)
#pragma unroll
          for (int r = 0; r < 4; ++r) {
            const int row_t = wr * 128 + m * 16 + lhalf * 4 + r;
            const int col_t = wc * 64 + n * 16 + lmod;
            if (row_t == col_t)
              diag[(mt >> 5) * BN_ + (mt & 31) * 256 + row_t] =
                  (float)acc[m][n][r] * INVQ;
          }
    }
#pragma unroll
    for (int m = 0; m < 8; ++m)
#pragma unroll
      for (int n = 0; n < 4; ++n)
#pragma unroll
        for (int r = 0; r < 4; ++r)
          rsum[m][r] += __builtin_amdgcn_exp2f((float)acc[m][n][r] * KQ);
  }

  // ---- final: reduce across 16 col-lanes, then atomicAdd ----
#pragma unroll
  for (int m = 0; m < 8; ++m)
#pragma unroll
    for (int r = 0; r < 4; ++r) {
      float v = rsum[m][r];
      v += __shfl_xor(v, 1, 64);
      v += __shfl_xor(v, 2, 64);
      v += __shfl_xor(v, 4, 64);
      v += __shfl_xor(v, 8, 64);
      if (lmod == 0)
        atomicAdd(&sumexp[(mt >> 5) * BN_ + (mt & 31) * 256 + wr * 128 + m * 16 + lhalf * 4 + r], v);
    }
#undef STAGE
#undef LD16
#undef UNIT
}

// ---------------- Kernel 3: CE = mean(log(sumexp) - diag) ----------------
__global__ __launch_bounds__(1024) void finalize_kernel(
    const float* __restrict__ sumexp, const float* __restrict__ diag,
    float* __restrict__ out) {
  const int tid = threadIdx.x;
  float s = 0.0f;
  for (int i = tid; i < 2 * BN_; i += 1024) s += logf(sumexp[i]) - diag[i];
#pragma unroll
  for (int mk = 32; mk >= 1; mk >>= 1) s += __shfl_xor(s, mk, 64);
  __shared__ float red[16];
  if ((tid & 63) == 0) red[tid >> 6] = s;
  __syncthreads();
  if (tid == 0) {
    float t = 0.f;
#pragma unroll
    for (int j = 0; j < 16; ++j) t += red[j];
    out[0] = t * (1.0f / (float)BN_);
  }
}

extern "C" void kernel_launch(void* const* d_in, const int* in_sizes, int n_in,
                              void* d_out, int out_size, void* d_ws, size_t ws_size,
                              hipStream_t stream) {
  const float* hf = (const float*)d_in[0];
  const float* lf = (const float*)d_in[1];
  const float* af = (const float*)d_in[2];

  char* ws = (char*)d_ws;
  const size_t nmat = (size_t)BN_ * DK_;                 // 2M elems, 2MB as i8
  unsigned char* qbase = (unsigned char*)ws;             // hq(2MB) lq(2MB) aq(2MB)
  unsigned char* hl = qbase;                             // stacked A [16384][256]
  unsigned char* an = qbase + 2 * nmat;
  float* sumexp = (float*)(ws + 3 * nmat);               // 64 KB [16384]
  float* diag = sumexp + 2 * BN_;                        // 64 KB [16384]

  hipFuncSetAttribute((const void*)gemm_lse_kernel,
                      hipFuncAttributeMaxDynamicSharedMemorySize, 131072);

  hipMemsetAsync(sumexp, 0, 2 * BN_ * sizeof(float), stream);
  norm_kernel<<<(3 * BN_) / 4, 256, 0, stream>>>(hf, lf, af, qbase);
  gemm_lse_kernel<<<256, 512, 131072, stream>>>(hl, an, sumexp, diag);
  finalize_kernel<<<1, 1024, 0, stream>>>(sumexp, diag, (float*)d_out);
}